// Round 5
// baseline (413.168 us; speedup 1.0000x reference)
//
#include <hip/hip_runtime.h>

typedef unsigned short u16;
typedef unsigned int u32;

typedef __bf16 bf16x8 __attribute__((ext_vector_type(8)));
typedef float f32x4 __attribute__((ext_vector_type(4)));

#define OUT_F 4096
#define IN_F 4096
#define M_ROWS 4096              // 2 * 2048
#define NUM_GROUPS ((OUT_F * IN_F) / 32)   // 524288
#define KITERS (IN_F / 64)       // 64

// ---------- helpers ----------

__device__ __forceinline__ u16 f2bf(float f) {
    union { float f; u32 u; } c; c.f = f;
    u32 u = c.u;
    u += 0x7fffu + ((u >> 16) & 1u);   // round-to-nearest-even (finite inputs)
    return (u16)(u >> 16);
}

__device__ __forceinline__ u32 pk2(float a, float b) {
    return (u32)f2bf(a) | ((u32)f2bf(b) << 16);
}

// async global -> LDS, 16 bytes per lane (global_load_lds_dwordx4)
__device__ __forceinline__ void async_copy16(const u16* g, u16* l) {
    __builtin_amdgcn_global_load_lds(
        (const __attribute__((address_space(1))) u32*)g,
        (__attribute__((address_space(3))) u32*)l,
        16, 0, 0);
}

__device__ __forceinline__ int ld_flag(const int* f) {
    return __hip_atomic_load(f, __ATOMIC_ACQUIRE, __HIP_MEMORY_SCOPE_WORKGROUP);
}
__device__ __forceinline__ void inc_flag(int* f) {
    __hip_atomic_fetch_add(f, 1, __ATOMIC_RELEASE, __HIP_MEMORY_SCOPE_WORKGROUP);
}

// ---------- fused prep (unchanged from R4) ----------
__global__ __launch_bounds__(256) void prep_kernel(
        const float* __restrict__ x, const int* __restrict__ q,
        const float* __restrict__ scales,
        u16* __restrict__ W, u16* __restrict__ Xb) {
    int bid = blockIdx.x;
    int tid = threadIdx.x;
    if (bid < 8192) {
        int t = bid * 256 + tid;                 // [0, 2097152)
        int b0 = q[3 * t];
        int b1 = q[3 * t + 1];
        int b2 = q[3 * t + 2];
        float mv = scales[t >> 2];
        float s = mv * (2.0f / 7.0f);            // w = v*s - mv
        float o = -mv;

        int v0 = b0 & 7;
        int v1 = (b0 >> 3) & 7;
        int v2 = ((b0 >> 6) & 3) | ((b1 & 1) << 2);
        int v3 = (b1 >> 1) & 7;
        int v4 = (b1 >> 4) & 7;
        int v5 = ((b1 >> 7) & 1) | ((b2 & 3) << 1);
        int v6 = (b2 >> 2) & 7;
        int v7 = (b2 >> 5) & 7;
        uint4 w;
        w.x = pk2(fmaf((float)v0, s, o), fmaf((float)v1, s, o));
        w.y = pk2(fmaf((float)v2, s, o), fmaf((float)v3, s, o));
        w.z = pk2(fmaf((float)v4, s, o), fmaf((float)v5, s, o));
        w.w = pk2(fmaf((float)v6, s, o), fmaf((float)v7, s, o));
        ((uint4*)W)[t] = w;
    } else {
        int i = (bid - 8192) * 256 + tid;
        const float4* p = (const float4*)x + (size_t)i * 2;
        float4 u = p[0], v = p[1];
        uint4 w;
        w.x = pk2(u.x, u.y);
        w.y = pk2(u.z, u.w);
        w.z = pk2(v.x, v.y);
        w.w = pk2(v.z, v.w);
        ((uint4*)Xb)[i] = w;
    }
}

// ---------- bf16 GEMM, producer-consumer K-loop (no __syncthreads in loop) ----
// C[m][n] = sum_k A[m][k]*B[n][k] + bias[n]
// block = 256 threads (4 waves), tile 128x128, BK=64, MFMA 16x16x32.
// 3 LDS buffer sets (96 KB) -> 1 block/CU. Each wave stages its own quarter
// (32 A-rows + 32 B-rows = 8 global_load_lds) of each buffer, so its
// s_waitcnt vmcnt(0) waits ONLY its own loads, issued ~2 iters earlier.
// Cross-wave readiness via monotonically-increasing LDS epoch flags:
//   prod[b]: 4 * (#times buffer b fully produced); cons[b]: consumer dones.
// Schedule at iter k (b = k%3):
//   (a) spin prod[b]  >= 4*(k/3+1)      -- data for k present (all 4 quarters)
//   (b) ds_read frags + 32 MFMA
//   (c) cons[b] += 1 (lane 0)
//   (d) if k+1 < 64: s_waitcnt vmcnt(0); prod[(k+1)%3] += 1
//       (my loads for k+1 were issued at (e) of iter k-2 -> latency hidden)
//   (e) if k+3 < 64: spin cons[b] >= 4*(k/3+1); issue 8 async for k+3
// XOR-chunk swizzle as R4 (measured 0 conflicts).
__global__ __launch_bounds__(256) void gemm_bt_kernel(
        const u16* __restrict__ A, const u16* __restrict__ B,
        const float* __restrict__ bias, float* __restrict__ C) {
    __shared__ u16 sAB[3][2][128 * 64];   // [buffer][A/B][tile]
    __shared__ int prodf[3];
    __shared__ int consf[3];

    const int tid = threadIdx.x;
    const int lane = tid & 63;
    const int w = tid >> 6;          // wave 0..3
    const int wr = w >> 1;           // wave row 0..1
    const int wc = w & 1;            // wave col 0..1
    const int ln = lane & 15;
    const int quad = lane >> 4;

    const int mb = blockIdx.y * 128;
    const int nb = blockIdx.x * 128;

    if (tid < 3) { prodf[tid] = 0; consf[tid] = 0; }

    // staging geometry: this wave covers slots [w*256, w*256+256) of 1024
    // slot s: row = s>>3 (A/B row 0..127), pc = s&7, lc = pc ^ (row&7)
    int offg[4];   // element offset within matrix block (add ko)
    int offl[4];   // u16 offset within one tile
#pragma unroll
    for (int p = 0; p < 4; ++p) {
        int slot = w * 256 + p * 64 + lane;
        int row = slot >> 3;
        int pc = slot & 7;
        int lc = pc ^ (row & 7);
        offg[p] = row * IN_F + lc * 8;
        offl[p] = slot * 8;
    }
    const u16* baseA = A + (size_t)mb * IN_F;
    const u16* baseB = B + (size_t)nb * IN_F;

    float bj[4];
#pragma unroll
    for (int j = 0; j < 4; ++j)
        bj[j] = bias[nb + wc * 64 + j * 16 + ln];

    int arow[4], brow[4];
#pragma unroll
    for (int i = 0; i < 4; ++i) {
        arow[i] = (wr * 64 + i * 16 + ln) * 64;
        brow[i] = (wc * 64 + i * 16 + ln) * 64;
    }
    const int lnx = ln & 7;

    f32x4 acc[4][4];
#pragma unroll
    for (int i = 0; i < 4; ++i)
#pragma unroll
        for (int j = 0; j < 4; ++j) acc[i][j] = (f32x4)0.0f;

    __syncthreads();   // flags initialized

    // ---- prologue: stage k=0 (flagged), issue k=1, k=2 (flagged later) ----
#pragma unroll
    for (int p = 0; p < 4; ++p) {
        async_copy16(baseA + offg[p], &sAB[0][0][offl[p]]);
        async_copy16(baseB + offg[p], &sAB[0][1][offl[p]]);
    }
    __builtin_amdgcn_s_waitcnt(0x0F70);   // vmcnt(0), lgkm/exp unrestricted
    if (lane == 0) inc_flag(&prodf[0]);
#pragma unroll
    for (int p = 0; p < 4; ++p) {
        async_copy16(baseA + offg[p] + 64, &sAB[1][0][offl[p]]);
        async_copy16(baseB + offg[p] + 64, &sAB[1][1][offl[p]]);
    }
#pragma unroll
    for (int p = 0; p < 4; ++p) {
        async_copy16(baseA + offg[p] + 128, &sAB[2][0][offl[p]]);
        async_copy16(baseB + offg[p] + 128, &sAB[2][1][offl[p]]);
    }

    for (int k = 0; k < KITERS; ++k) {
        const int b = k - (k / 3) * 3;          // k % 3
        const int target = 4 * (k / 3 + 1);
        const u16* tA = &sAB[b][0][0];
        const u16* tB = &sAB[b][1][0];

        // (a) wait for all 4 quarters of buffer b
        while (ld_flag(&prodf[b]) < target) { }

        // (b) consume: 16 ds_read_b128 + 32 MFMA
#pragma unroll
        for (int kk = 0; kk < 2; ++kk) {
            const int pc8 = ((kk * 4 + quad) ^ lnx) * 8;
            bf16x8 av[4], bv[4];
#pragma unroll
            for (int i = 0; i < 4; ++i)
                av[i] = *(const bf16x8*)&tA[arow[i] + pc8];
#pragma unroll
            for (int j = 0; j < 4; ++j)
                bv[j] = *(const bf16x8*)&tB[brow[j] + pc8];
#pragma unroll
            for (int i = 0; i < 4; ++i)
#pragma unroll
                for (int j = 0; j < 4; ++j)
                    acc[i][j] = __builtin_amdgcn_mfma_f32_16x16x32_bf16(
                        av[i], bv[j], acc[i][j], 0, 0, 0);
        }

        // (c) signal done with buffer b for this use
        if (lane == 0) inc_flag(&consf[b]);

        // (d) finalize production of k+1 (my loads issued at (e) of k-2,
        //     or in the prologue) — vmcnt(0) covers only this wave's loads
        if (k + 1 < KITERS) {
            __builtin_amdgcn_s_waitcnt(0x0F70);
            if (lane == 0) inc_flag(&prodf[k + 1 - ((k + 1) / 3) * 3]);
        }

        // (e) start production of k+3 into buffer b (safe once all waves
        //     have consumed iteration k)
        if (k + 3 < KITERS) {
            while (ld_flag(&consf[b]) < target) { }
            const int ko = (k + 3) * 64;
#pragma unroll
            for (int p = 0; p < 4; ++p) {
                async_copy16(baseA + offg[p] + ko, &sAB[b][0][offl[p]]);
                async_copy16(baseB + offg[p] + ko, &sAB[b][1][offl[p]]);
            }
        }
    }

    // epilogue: each wave writes its private 64x64 subtile
#pragma unroll
    for (int i = 0; i < 4; ++i) {
        int mrow = mb + wr * 64 + i * 16 + quad * 4;
#pragma unroll
        for (int j = 0; j < 4; ++j) {
            int col = nb + wc * 64 + j * 16 + ln;
            float* cp = C + (size_t)mrow * OUT_F + col;
#pragma unroll
            for (int r = 0; r < 4; ++r)
                cp[(size_t)r * OUT_F] = acc[i][j][r] + bj[j];
        }
    }
}

extern "C" void kernel_launch(void* const* d_in, const int* in_sizes, int n_in,
                              void* d_out, int out_size, void* d_ws, size_t ws_size,
                              hipStream_t stream) {
    const float* x = (const float*)d_in[0];       // [2,2048,4096] fp32
    const int* wq = (const int*)d_in[1];          // [NUM_GROUPS*12]
    const float* wn = (const float*)d_in[2];      // [NUM_GROUPS]
    const float* bias = (const float*)d_in[3];    // [4096]
    float* out = (float*)d_out;                   // [2,2048,4096] fp32

    u16* Wb = (u16*)d_ws;                         // 32 MB
    u16* Xb = Wb + (size_t)OUT_F * IN_F;          // 32 MB

    prep_kernel<<<16384, 256, 0, stream>>>(x, wq, wn, Wb, Xb);
    gemm_bt_kernel<<<dim3(OUT_F / 128, M_ROWS / 128), 256, 0, stream>>>(
        Xb, Wb, bias, out);
}